// Round 9
// baseline (327.036 us; speedup 1.0000x reference)
//
#include <hip/hip_runtime.h>
#include <hip/hip_bf16.h>

// Problem: B=8, N=2048, C=320, H=5, D=64, SCALE=1/8. Inputs f32, output f32.
// out = proj( softmax(Q K^T / 8) V ), qkv = x @ w_qkv^T (w stored [out,in]).
// QKV GEMM: plain bf16. Proj GEMM: split-bf16 hi/lo 3-term MFMA.
// Attention: Q pre-scaled by 0.125*log2(e) -> softmax = bare exp2. K/V in
// MFMA-fragment order (one coalesced dwordx4 per fragment). 2-wave blocks,
// KV-split halves, end-of-kernel LDS combine. Round 9: pointer-increment
// global addressing + immediate-offset LDS (no XOR swizzle; stride-72 pad
// keeps conflicts in the free 2-way regime) + waves_per_eu(4) to hold the
// 128-VGPR / 4-waves-per-SIMD occupancy tier.
// NOTE: launch_bounds(128,4) is POISON (forces 64 VGPR -> spills, round 7).

typedef __attribute__((ext_vector_type(8))) short bf16x8;   // 8 bf16 = 4 VGPRs
typedef __attribute__((ext_vector_type(4))) float f32x4;

#define MFMA(a, b, c) __builtin_amdgcn_mfma_f32_16x16x32_bf16((a), (b), (c), 0, 0, 0)

// Q pre-scale: (1/8) * log2(e)
#define QSCALE 0.18033688322643216f

static __device__ __forceinline__ bf16x8 ld8(const __hip_bfloat16* p) {
    return *reinterpret_cast<const bf16x8*>(p);
}

static __device__ __forceinline__ void split_bf16(float v, __hip_bfloat16& h,
                                                  __hip_bfloat16& l) {
    __hip_bfloat16 hh = __float2bfloat16(v);
    h = hh;
    l = __float2bfloat16(v - __bfloat162float(hh));
}

// ---------------------------------------------------------------------------
// Kernel 0: x,w_qkv -> plain bf16 (float4-vectorized); w_proj -> hi/lo pair.
// ---------------------------------------------------------------------------
__global__ __launch_bounds__(256)
void split_inputs(const float* __restrict__ x, const float* __restrict__ wq,
                  const float* __restrict__ wp,
                  __hip_bfloat16* __restrict__ xb, __hip_bfloat16* __restrict__ wqb,
                  __hip_bfloat16* __restrict__ wph, __hip_bfloat16* __restrict__ wpl)
{
    const size_t tid = (size_t)blockIdx.x * blockDim.x + threadIdx.x;
    const size_t stride = (size_t)gridDim.x * blockDim.x;
    const float4* x4 = (const float4*)x;
    ushort4* xb4 = (ushort4*)xb;
    for (size_t i = tid; i < 1310720u; i += stride) {   // 5242880/4
        float4 v = x4[i];
        __hip_bfloat16 b0 = __float2bfloat16(v.x), b1 = __float2bfloat16(v.y);
        __hip_bfloat16 b2 = __float2bfloat16(v.z), b3 = __float2bfloat16(v.w);
        ushort4 u;
        u.x = *reinterpret_cast<unsigned short*>(&b0);
        u.y = *reinterpret_cast<unsigned short*>(&b1);
        u.z = *reinterpret_cast<unsigned short*>(&b2);
        u.w = *reinterpret_cast<unsigned short*>(&b3);
        xb4[i] = u;
    }
    for (size_t i = tid; i < 307200u; i += stride) wqb[i] = __float2bfloat16(wq[i]);
    for (size_t i = tid; i < 102400u; i += stride) split_bf16(wp[i], wph[i], wpl[i]);
}

// ---------------------------------------------------------------------------
// Kernel 1: QKV GEMM, plain bf16, BK=64. out[m][n] = sum_k x[m][k]*w[n][k].
// Q written row-major [bh][n][d] PRE-SCALED by QSCALE.
// K in B-fragment order K', V in B-fragment order V'.
// ---------------------------------------------------------------------------
__global__ __launch_bounds__(256)
void qkv_kernel(const __hip_bfloat16* __restrict__ x,
                const __hip_bfloat16* __restrict__ w,
                __hip_bfloat16* __restrict__ qout,
                __hip_bfloat16* __restrict__ kp,
                __hip_bfloat16* __restrict__ vp)
{
    __shared__ __align__(16) __hip_bfloat16 As[128 * 72];  // 128x64, pad->72
    __shared__ __align__(16) __hip_bfloat16 Bs[64 * 72];   // 64x64,  pad->72

    const int tid  = threadIdx.x;
    const int wv   = tid >> 6;
    const int lane = tid & 63;
    const int quad = lane >> 4;
    const int col  = lane & 15;
    const int m0   = blockIdx.x * 128;
    const int n0   = blockIdx.y * 64;

    f32x4 acc[2][4];
#pragma unroll
    for (int i = 0; i < 2; ++i)
#pragma unroll
        for (int j = 0; j < 4; ++j) acc[i][j] = (f32x4){0.f, 0.f, 0.f, 0.f};

    for (int k0 = 0; k0 < 320; k0 += 64) {
        __syncthreads();
#pragma unroll
        for (int i = 0; i < 4; ++i) {
            int ch = tid + i * 256;
            int r = ch >> 3, sg = ch & 7;
            *reinterpret_cast<float4*>(&As[r * 72 + sg * 8]) =
                *reinterpret_cast<const float4*>(&x[(m0 + r) * 320 + k0 + sg * 8]);
        }
#pragma unroll
        for (int i = 0; i < 2; ++i) {
            int ch = tid + i * 256;
            int r = ch >> 3, sg = ch & 7;
            *reinterpret_cast<float4*>(&Bs[r * 72 + sg * 8]) =
                *reinterpret_cast<const float4*>(&w[(n0 + r) * 320 + k0 + sg * 8]);
        }
        __syncthreads();

#pragma unroll
        for (int hf = 0; hf < 2; ++hf) {
            bf16x8 a0 = ld8(&As[(wv * 32 + col) * 72 + hf * 32 + quad * 8]);
            bf16x8 a1 = ld8(&As[(wv * 32 + 16 + col) * 72 + hf * 32 + quad * 8]);
#pragma unroll
            for (int nt = 0; nt < 4; ++nt) {
                bf16x8 b = ld8(&Bs[(nt * 16 + col) * 72 + hf * 32 + quad * 8]);
                acc[0][nt] = MFMA(a0, b, acc[0][nt]);
                acc[1][nt] = MFMA(a1, b, acc[1][nt]);
            }
        }
    }

    const int s = blockIdx.y / 5;   // 0=Q,1=K,2=V
    const int h = blockIdx.y % 5;
#pragma unroll
    for (int mt = 0; mt < 2; ++mt) {
#pragma unroll
        for (int nt = 0; nt < 4; ++nt) {
#pragma unroll
            for (int r = 0; r < 4; ++r) {
                int m = m0 + wv * 32 + mt * 16 + quad * 4 + r;
                int d = nt * 16 + col;
                int b = m >> 11, n = m & 2047;
                int bh = b * 5 + h;
                float val = acc[mt][nt][r];
                if (s == 0) {
                    qout[((size_t)bh * 2048 + n) * 64 + d] =
                        __float2bfloat16(val * QSCALE);
                } else if (s == 1) {
                    int p = n >> 6, nn = n & 63;
                    size_t a = ((size_t)(bh * 32 + p) * 8 + (d >> 5) * 4 + (nn >> 4)) * 512
                             + (((d >> 3) & 3) * 16 + (nn & 15)) * 8 + (d & 7);
                    kp[a] = __float2bfloat16(val);
                } else {
                    int p = n >> 6;
                    size_t a = ((size_t)(bh * 32 + p) * 8 + ((n >> 5) & 1) * 4 + (d >> 4)) * 512
                             + (((n >> 3) & 3) * 16 + (d & 15)) * 8 + (n & 7);
                    vp[a] = __float2bfloat16(val);
                }
            }
        }
    }
}

// ---------------------------------------------------------------------------
// Kernel 2: flash attention, fragment-order K'/V', KV-split 2-wave blocks.
// Pointer-increment global addressing (+4096 elem/tile, imm f*512 offsets);
// lane-fixed LDS bases + compile-time imm offsets (no per-op VALU).
// Unconditional K prefetch (one-past read lands in adjacent buffer).
// ---------------------------------------------------------------------------
__global__ __launch_bounds__(128)
__attribute__((amdgpu_waves_per_eu(4)))
void attn_kernel(const __hip_bfloat16* __restrict__ Q,
                 const __hip_bfloat16* __restrict__ Kp,
                 const __hip_bfloat16* __restrict__ Vp,
                 __hip_bfloat16* __restrict__ A2h,
                 __hip_bfloat16* __restrict__ A2l)
{
    // union: per-wave Ps (2 x 32x72 bf16 = 9216 B) / end-of-kernel combine
    __shared__ __align__(16) unsigned char smraw[9216];

    const int tid  = threadIdx.x;
    const int wv   = tid >> 6;
    const int lane = tid & 63;
    const int quad = lane >> 4;
    const int col  = lane & 15;
    const int bh = blockIdx.y, b = bh / 5, h = bh % 5;
    const int q0 = blockIdx.x * 32;
    const int t0 = wv * 16;

    __hip_bfloat16* Ps = (__hip_bfloat16*)smraw + wv * 2304;       // 32*72
    // lane-fixed LDS bases; all per-op offsets are compile-time immediates
    __hip_bfloat16* ps_w = Ps + (quad * 4) * 72 + col;             // + (mt*16+r)*72 + nt*16
    const __hip_bfloat16* ps_r = Ps + col * 72 + quad * 8;         // + mt*1152 + kk*32

    // pointer-increment K/V bases (fragment-order panels: 4096 elem each)
    const __hip_bfloat16* kt = Kp + (size_t)bh * 131072 + (size_t)t0 * 4096 + lane * 8;
    const __hip_bfloat16* vt = Vp + (size_t)bh * 131072 + (size_t)t0 * 4096 + lane * 8;
    const __hip_bfloat16* Qh = Q + (size_t)bh * 131072;

    // Q fragments (A-layout): rows q0+mt*16+col, k = hf*32+quad*8+j
    bf16x8 qf[2][2];
#pragma unroll
    for (int mt = 0; mt < 2; ++mt)
#pragma unroll
        for (int hf = 0; hf < 2; ++hf)
            qf[mt][hf] = ld8(&Qh[(q0 + mt * 16 + col) * 64 + hf * 32 + quad * 8]);

    f32x4 lp[2];
    f32x4 o[2][4];
#pragma unroll
    for (int mt = 0; mt < 2; ++mt) {
        lp[mt] = (f32x4){0.f, 0.f, 0.f, 0.f};
#pragma unroll
        for (int dt = 0; dt < 4; ++dt) o[mt][dt] = (f32x4){0.f, 0.f, 0.f, 0.f};
    }

    // preload first K panel
    bf16x8 ka[8];
#pragma unroll
    for (int f = 0; f < 8; ++f) ka[f] = ld8(kt + f * 512);
    kt += 4096;

    for (int t = 0; t < 16; ++t) {
        // QK^T: ka[f] = frag(hf=f>>2, nt=f&3)
        f32x4 s[2][4];
#pragma unroll
        for (int mt = 0; mt < 2; ++mt)
#pragma unroll
            for (int nt = 0; nt < 4; ++nt) {
                f32x4 z = (f32x4){0.f, 0.f, 0.f, 0.f};
                z = MFMA(qf[mt][0], ka[nt], z);
                z = MFMA(qf[mt][1], ka[4 + nt], z);
                s[mt][nt] = z;
            }

        // V loads for THIS tile (in flight across exp; PV waits on them)
        bf16x8 va[8];
#pragma unroll
        for (int f = 0; f < 8; ++f) va[f] = ld8(vt + f * 512);
        vt += 4096;

        // unconditional prefetch of next K panel (one-past read is harmless:
        // lands in the adjacent allocated vp buffer on the final panel)
#pragma unroll
        for (int f = 0; f < 8; ++f) ka[f] = ld8(kt + f * 512);
        kt += 4096;

        // softmax: p = exp2(z); C-layout -> Ps via imm-offset stores
#pragma unroll
        for (int mt = 0; mt < 2; ++mt)
#pragma unroll
            for (int nt = 0; nt < 4; ++nt) {
                f32x4 pv;
#pragma unroll
                for (int r = 0; r < 4; ++r)
                    pv[r] = __builtin_amdgcn_exp2f(s[mt][nt][r]);
                lp[mt] += pv;
#pragma unroll
                for (int r = 0; r < 4; ++r)
                    ps_w[(mt * 16 + r) * 72 + nt * 16] = __float2bfloat16(pv[r]);
            }
        __asm__ volatile("s_waitcnt lgkmcnt(0)" ::: "memory");

        // PV: A-layout P reads (imm offsets); va[f] = frag(kk=f>>2, dt=f&3)
#pragma unroll
        for (int mt = 0; mt < 2; ++mt)
#pragma unroll
            for (int kk = 0; kk < 2; ++kk) {
                bf16x8 pf = ld8(ps_r + mt * 1152 + kk * 32);
#pragma unroll
                for (int dt = 0; dt < 4; ++dt)
                    o[mt][dt] = MFMA(pf, va[kk * 4 + dt], o[mt][dt]);
            }
    }

    // per-wave row-sum over the 16-lane col group
    float lval[2][4];
#pragma unroll
    for (int mt = 0; mt < 2; ++mt)
#pragma unroll
        for (int r = 0; r < 4; ++r) {
            float v = lp[mt][r];
#pragma unroll
            for (int off = 1; off < 16; off <<= 1)
                v += __shfl_xor(v, off, 64);
            lval[mt][r] = v;
        }

    // combine the two KV-half partials through LDS
    float* cbo = (float*)smraw;        // [32][64]
    float* cbl = cbo + 2048;           // [32]
    __syncthreads();                   // both waves done with Ps
    if (wv == 1) {
#pragma unroll
        for (int mt = 0; mt < 2; ++mt)
#pragma unroll
            for (int dt = 0; dt < 4; ++dt)
#pragma unroll
                for (int r = 0; r < 4; ++r)
                    cbo[(mt * 16 + quad * 4 + r) * 64 + dt * 16 + col] = o[mt][dt][r];
        if (col == 0)
#pragma unroll
            for (int mt = 0; mt < 2; ++mt)
#pragma unroll
                for (int r = 0; r < 4; ++r)
                    cbl[mt * 16 + quad * 4 + r] = lval[mt][r];
    }
    __syncthreads();
    if (wv == 0) {
#pragma unroll
        for (int mt = 0; mt < 2; ++mt) {
#pragma unroll
            for (int r = 0; r < 4; ++r) {
                int row = mt * 16 + quad * 4 + r;
                float inv = 1.0f / (lval[mt][r] + cbl[row]);
                int grow = q0 + row;
#pragma unroll
                for (int dt = 0; dt < 4; ++dt) {
                    int d = dt * 16 + col;
                    float val = (o[mt][dt][r] + cbo[row * 64 + d]) * inv;
                    size_t idx = ((size_t)(b * 2048 + grow)) * 320 + h * 64 + d;
                    split_bf16(val, A2h[idx], A2l[idx]);
                }
            }
        }
    }
}

// ---------------------------------------------------------------------------
// Kernel 3: output projection, split-precision (error-critical GEMM).
// out[m][n] = sum_k a2[m][k]*w[n][k] + bias[n], M=16384, N=320, K=320.
// ---------------------------------------------------------------------------
__global__ __launch_bounds__(256)
void proj_kernel(const __hip_bfloat16* __restrict__ ah, const __hip_bfloat16* __restrict__ al,
                 const __hip_bfloat16* __restrict__ wh, const __hip_bfloat16* __restrict__ wl,
                 const float* __restrict__ bias,
                 float* __restrict__ out)
{
    __shared__ __align__(16) __hip_bfloat16 Ash[128 * 40];
    __shared__ __align__(16) __hip_bfloat16 Asl[128 * 40];
    __shared__ __align__(16) __hip_bfloat16 Bsh[64 * 40];
    __shared__ __align__(16) __hip_bfloat16 Bsl[64 * 40];

    const int tid  = threadIdx.x;
    const int wv   = tid >> 6;
    const int lane = tid & 63;
    const int quad = lane >> 4;
    const int col  = lane & 15;
    const int m0   = blockIdx.x * 128;
    const int n0   = blockIdx.y * 64;

    f32x4 acc[2][4];
#pragma unroll
    for (int i = 0; i < 2; ++i)
#pragma unroll
        for (int j = 0; j < 4; ++j) acc[i][j] = (f32x4){0.f, 0.f, 0.f, 0.f};

    for (int k0 = 0; k0 < 320; k0 += 32) {
        __syncthreads();
#pragma unroll
        for (int i = 0; i < 2; ++i) {
            int ch = tid + i * 256;
            int r = ch >> 2, sg = ch & 3;
            *reinterpret_cast<float4*>(&Ash[r * 40 + sg * 8]) =
                *reinterpret_cast<const float4*>(&ah[(m0 + r) * 320 + k0 + sg * 8]);
            *reinterpret_cast<float4*>(&Asl[r * 40 + sg * 8]) =
                *reinterpret_cast<const float4*>(&al[(m0 + r) * 320 + k0 + sg * 8]);
        }
        {
            int r = tid >> 2, sg = tid & 3;
            *reinterpret_cast<float4*>(&Bsh[r * 40 + sg * 8]) =
                *reinterpret_cast<const float4*>(&wh[(n0 + r) * 320 + k0 + sg * 8]);
            *reinterpret_cast<float4*>(&Bsl[r * 40 + sg * 8]) =
                *reinterpret_cast<const float4*>(&wl[(n0 + r) * 320 + k0 + sg * 8]);
        }
        __syncthreads();

        bf16x8 a0h = ld8(&Ash[(wv * 32 + col) * 40 + quad * 8]);
        bf16x8 a1h = ld8(&Ash[(wv * 32 + 16 + col) * 40 + quad * 8]);
        bf16x8 a0l = ld8(&Asl[(wv * 32 + col) * 40 + quad * 8]);
        bf16x8 a1l = ld8(&Asl[(wv * 32 + 16 + col) * 40 + quad * 8]);
#pragma unroll
        for (int nt = 0; nt < 4; ++nt) {
            bf16x8 bh = ld8(&Bsh[(nt * 16 + col) * 40 + quad * 8]);
            bf16x8 bl = ld8(&Bsl[(nt * 16 + col) * 40 + quad * 8]);
            acc[0][nt] = MFMA(a0h, bh, acc[0][nt]);
            acc[0][nt] = MFMA(a0h, bl, acc[0][nt]);
            acc[0][nt] = MFMA(a0l, bh, acc[0][nt]);
            acc[1][nt] = MFMA(a1h, bh, acc[1][nt]);
            acc[1][nt] = MFMA(a1h, bl, acc[1][nt]);
            acc[1][nt] = MFMA(a1l, bh, acc[1][nt]);
        }
    }

#pragma unroll
    for (int nt = 0; nt < 4; ++nt) {
        float bv = bias[n0 + nt * 16 + col];
#pragma unroll
        for (int mt = 0; mt < 2; ++mt) {
#pragma unroll
            for (int r = 0; r < 4; ++r) {
                int m = m0 + wv * 32 + mt * 16 + quad * 4 + r;
                out[(size_t)m * 320 + n0 + nt * 16 + col] = acc[mt][nt][r] + bv;
            }
        }
    }
}

// ---------------------------------------------------------------------------
extern "C" void kernel_launch(void* const* d_in, const int* in_sizes, int n_in,
                              void* d_out, int out_size, void* d_ws, size_t ws_size,
                              hipStream_t stream)
{
    const float* x      = (const float*)d_in[0];  // [8,2048,320]
    const float* w_qkv  = (const float*)d_in[1];  // [960,320]
    const float* w_proj = (const float*)d_in[2];  // [320,320]
    const float* b_proj = (const float*)d_in[3];  // [320]
    float* out = (float*)d_out;                   // [8,2048,320] f32

    const size_t NX = 5242880, NWQ = 307200, NWP = 102400;
    __hip_bfloat16* xb  = (__hip_bfloat16*)d_ws;  // reused as a2h after qkv
    __hip_bfloat16* wqb = xb + NX;
    __hip_bfloat16* wph = wqb + NWQ;
    __hip_bfloat16* wpl = wph + NWP;
    __hip_bfloat16* q   = wpl + NWP;              // [bh][n][d], pre-scaled
    __hip_bfloat16* kp  = q + NX;                 // K' fragment order
    __hip_bfloat16* vp  = kp + NX;                // V' fragment order (after kp:
                                                  //  one-past K prefetch lands here)
    __hip_bfloat16* a2l = vp + NX;                // [B,N,C] lo half
    __hip_bfloat16* a2h = xb;                     // alias: x dead after qkv

    split_inputs<<<1024, 256, 0, stream>>>(x, w_qkv, w_proj, xb, wqb, wph, wpl);
    qkv_kernel<<<dim3(128, 15), 256, 0, stream>>>(xb, wqb, q, kp, vp);
    attn_kernel<<<dim3(64, 40), 128, 0, stream>>>(q, kp, vp, a2h, a2l);
    proj_kernel<<<dim3(128, 5), 256, 0, stream>>>(a2h, a2l, wph, wpl, b_proj, out);
}

// Round 10
// 190.806 us; speedup vs baseline: 1.7140x; 1.7140x over previous
//
#include <hip/hip_runtime.h>
#include <hip/hip_bf16.h>

// Problem: B=8, N=2048, C=320, H=5, D=64, SCALE=1/8. Inputs f32, output f32.
// out = proj( softmax(Q K^T / 8) V ), qkv = x @ w_qkv^T (w stored [out,in]).
// QKV GEMM: plain bf16. Proj GEMM: split-bf16 hi/lo 3-term MFMA.
// Attention: Q pre-scaled by 0.125*log2(e) -> softmax = bare exp2. K/V in
// MFMA-fragment order (one coalesced dwordx4 per fragment). 2-wave blocks,
// KV-split halves, end-of-kernel LDS combine. Pointer-increment global
// addressing + immediate-offset LDS (stride-72 pad, conflicts in free 2-way
// regime).
// TOOLCHAIN RULE (rounds 7 & 9): ANY min-occupancy hint — launch_bounds 2nd
// arg OR amdgpu_waves_per_eu — clamps this kernel to the 64-VGPR tier and
// spills ~80 live regs to scratch (FETCH 87->250+ MB, 2.3-3x slower).
// The allocator must float (~132 VGPR, 3 waves/SIMD).

typedef __attribute__((ext_vector_type(8))) short bf16x8;   // 8 bf16 = 4 VGPRs
typedef __attribute__((ext_vector_type(4))) float f32x4;

#define MFMA(a, b, c) __builtin_amdgcn_mfma_f32_16x16x32_bf16((a), (b), (c), 0, 0, 0)

// Q pre-scale: (1/8) * log2(e)
#define QSCALE 0.18033688322643216f

static __device__ __forceinline__ bf16x8 ld8(const __hip_bfloat16* p) {
    return *reinterpret_cast<const bf16x8*>(p);
}

static __device__ __forceinline__ void split_bf16(float v, __hip_bfloat16& h,
                                                  __hip_bfloat16& l) {
    __hip_bfloat16 hh = __float2bfloat16(v);
    h = hh;
    l = __float2bfloat16(v - __bfloat162float(hh));
}

// ---------------------------------------------------------------------------
// Kernel 0: x,w_qkv -> plain bf16 (float4-vectorized); w_proj -> hi/lo pair.
// ---------------------------------------------------------------------------
__global__ __launch_bounds__(256)
void split_inputs(const float* __restrict__ x, const float* __restrict__ wq,
                  const float* __restrict__ wp,
                  __hip_bfloat16* __restrict__ xb, __hip_bfloat16* __restrict__ wqb,
                  __hip_bfloat16* __restrict__ wph, __hip_bfloat16* __restrict__ wpl)
{
    const size_t tid = (size_t)blockIdx.x * blockDim.x + threadIdx.x;
    const size_t stride = (size_t)gridDim.x * blockDim.x;
    const float4* x4 = (const float4*)x;
    ushort4* xb4 = (ushort4*)xb;
    for (size_t i = tid; i < 1310720u; i += stride) {   // 5242880/4
        float4 v = x4[i];
        __hip_bfloat16 b0 = __float2bfloat16(v.x), b1 = __float2bfloat16(v.y);
        __hip_bfloat16 b2 = __float2bfloat16(v.z), b3 = __float2bfloat16(v.w);
        ushort4 u;
        u.x = *reinterpret_cast<unsigned short*>(&b0);
        u.y = *reinterpret_cast<unsigned short*>(&b1);
        u.z = *reinterpret_cast<unsigned short*>(&b2);
        u.w = *reinterpret_cast<unsigned short*>(&b3);
        xb4[i] = u;
    }
    for (size_t i = tid; i < 307200u; i += stride) wqb[i] = __float2bfloat16(wq[i]);
    for (size_t i = tid; i < 102400u; i += stride) split_bf16(wp[i], wph[i], wpl[i]);
}

// ---------------------------------------------------------------------------
// Kernel 1: QKV GEMM, plain bf16, BK=64. out[m][n] = sum_k x[m][k]*w[n][k].
// Q written row-major [bh][n][d] PRE-SCALED by QSCALE.
// K in B-fragment order K', V in B-fragment order V'.
// ---------------------------------------------------------------------------
__global__ __launch_bounds__(256)
void qkv_kernel(const __hip_bfloat16* __restrict__ x,
                const __hip_bfloat16* __restrict__ w,
                __hip_bfloat16* __restrict__ qout,
                __hip_bfloat16* __restrict__ kp,
                __hip_bfloat16* __restrict__ vp)
{
    __shared__ __align__(16) __hip_bfloat16 As[128 * 72];  // 128x64, pad->72
    __shared__ __align__(16) __hip_bfloat16 Bs[64 * 72];   // 64x64,  pad->72

    const int tid  = threadIdx.x;
    const int wv   = tid >> 6;
    const int lane = tid & 63;
    const int quad = lane >> 4;
    const int col  = lane & 15;
    const int m0   = blockIdx.x * 128;
    const int n0   = blockIdx.y * 64;

    f32x4 acc[2][4];
#pragma unroll
    for (int i = 0; i < 2; ++i)
#pragma unroll
        for (int j = 0; j < 4; ++j) acc[i][j] = (f32x4){0.f, 0.f, 0.f, 0.f};

    for (int k0 = 0; k0 < 320; k0 += 64) {
        __syncthreads();
#pragma unroll
        for (int i = 0; i < 4; ++i) {
            int ch = tid + i * 256;
            int r = ch >> 3, sg = ch & 7;
            *reinterpret_cast<float4*>(&As[r * 72 + sg * 8]) =
                *reinterpret_cast<const float4*>(&x[(m0 + r) * 320 + k0 + sg * 8]);
        }
#pragma unroll
        for (int i = 0; i < 2; ++i) {
            int ch = tid + i * 256;
            int r = ch >> 3, sg = ch & 7;
            *reinterpret_cast<float4*>(&Bs[r * 72 + sg * 8]) =
                *reinterpret_cast<const float4*>(&w[(n0 + r) * 320 + k0 + sg * 8]);
        }
        __syncthreads();

#pragma unroll
        for (int hf = 0; hf < 2; ++hf) {
            bf16x8 a0 = ld8(&As[(wv * 32 + col) * 72 + hf * 32 + quad * 8]);
            bf16x8 a1 = ld8(&As[(wv * 32 + 16 + col) * 72 + hf * 32 + quad * 8]);
#pragma unroll
            for (int nt = 0; nt < 4; ++nt) {
                bf16x8 b = ld8(&Bs[(nt * 16 + col) * 72 + hf * 32 + quad * 8]);
                acc[0][nt] = MFMA(a0, b, acc[0][nt]);
                acc[1][nt] = MFMA(a1, b, acc[1][nt]);
            }
        }
    }

    const int s = blockIdx.y / 5;   // 0=Q,1=K,2=V
    const int h = blockIdx.y % 5;
#pragma unroll
    for (int mt = 0; mt < 2; ++mt) {
#pragma unroll
        for (int nt = 0; nt < 4; ++nt) {
#pragma unroll
            for (int r = 0; r < 4; ++r) {
                int m = m0 + wv * 32 + mt * 16 + quad * 4 + r;
                int d = nt * 16 + col;
                int b = m >> 11, n = m & 2047;
                int bh = b * 5 + h;
                float val = acc[mt][nt][r];
                if (s == 0) {
                    qout[((size_t)bh * 2048 + n) * 64 + d] =
                        __float2bfloat16(val * QSCALE);
                } else if (s == 1) {
                    int p = n >> 6, nn = n & 63;
                    size_t a = ((size_t)(bh * 32 + p) * 8 + (d >> 5) * 4 + (nn >> 4)) * 512
                             + (((d >> 3) & 3) * 16 + (nn & 15)) * 8 + (d & 7);
                    kp[a] = __float2bfloat16(val);
                } else {
                    int p = n >> 6;
                    size_t a = ((size_t)(bh * 32 + p) * 8 + ((n >> 5) & 1) * 4 + (d >> 4)) * 512
                             + (((n >> 3) & 3) * 16 + (d & 15)) * 8 + (n & 7);
                    vp[a] = __float2bfloat16(val);
                }
            }
        }
    }
}

// ---------------------------------------------------------------------------
// Kernel 2: flash attention, fragment-order K'/V', KV-split 2-wave blocks.
// Pointer-increment global addressing (+4096 elem/tile, imm f*512 offsets);
// lane-fixed LDS bases + compile-time imm offsets (no per-op VALU).
// Unconditional K prefetch (one-past read lands in adjacent buffer).
// NO occupancy hints — allocator must float (see toolchain rule above).
// ---------------------------------------------------------------------------
__global__ __launch_bounds__(128)
void attn_kernel(const __hip_bfloat16* __restrict__ Q,
                 const __hip_bfloat16* __restrict__ Kp,
                 const __hip_bfloat16* __restrict__ Vp,
                 __hip_bfloat16* __restrict__ A2h,
                 __hip_bfloat16* __restrict__ A2l)
{
    // union: per-wave Ps (2 x 32x72 bf16 = 9216 B) / end-of-kernel combine
    __shared__ __align__(16) unsigned char smraw[9216];

    const int tid  = threadIdx.x;
    const int wv   = tid >> 6;
    const int lane = tid & 63;
    const int quad = lane >> 4;
    const int col  = lane & 15;
    const int bh = blockIdx.y, b = bh / 5, h = bh % 5;
    const int q0 = blockIdx.x * 32;
    const int t0 = wv * 16;

    __hip_bfloat16* Ps = (__hip_bfloat16*)smraw + wv * 2304;       // 32*72
    // lane-fixed LDS bases; all per-op offsets are compile-time immediates
    __hip_bfloat16* ps_w = Ps + (quad * 4) * 72 + col;             // + (mt*16+r)*72 + nt*16
    const __hip_bfloat16* ps_r = Ps + col * 72 + quad * 8;         // + mt*1152 + kk*32

    // pointer-increment K/V bases (fragment-order panels: 4096 elem each)
    const __hip_bfloat16* kt = Kp + (size_t)bh * 131072 + (size_t)t0 * 4096 + lane * 8;
    const __hip_bfloat16* vt = Vp + (size_t)bh * 131072 + (size_t)t0 * 4096 + lane * 8;
    const __hip_bfloat16* Qh = Q + (size_t)bh * 131072;

    // Q fragments (A-layout): rows q0+mt*16+col, k = hf*32+quad*8+j
    bf16x8 qf[2][2];
#pragma unroll
    for (int mt = 0; mt < 2; ++mt)
#pragma unroll
        for (int hf = 0; hf < 2; ++hf)
            qf[mt][hf] = ld8(&Qh[(q0 + mt * 16 + col) * 64 + hf * 32 + quad * 8]);

    f32x4 lp[2];
    f32x4 o[2][4];
#pragma unroll
    for (int mt = 0; mt < 2; ++mt) {
        lp[mt] = (f32x4){0.f, 0.f, 0.f, 0.f};
#pragma unroll
        for (int dt = 0; dt < 4; ++dt) o[mt][dt] = (f32x4){0.f, 0.f, 0.f, 0.f};
    }

    // preload first K panel
    bf16x8 ka[8];
#pragma unroll
    for (int f = 0; f < 8; ++f) ka[f] = ld8(kt + f * 512);
    kt += 4096;

    for (int t = 0; t < 16; ++t) {
        // QK^T: ka[f] = frag(hf=f>>2, nt=f&3)
        f32x4 s[2][4];
#pragma unroll
        for (int mt = 0; mt < 2; ++mt)
#pragma unroll
            for (int nt = 0; nt < 4; ++nt) {
                f32x4 z = (f32x4){0.f, 0.f, 0.f, 0.f};
                z = MFMA(qf[mt][0], ka[nt], z);
                z = MFMA(qf[mt][1], ka[4 + nt], z);
                s[mt][nt] = z;
            }

        // V loads for THIS tile (in flight across exp; PV waits on them)
        bf16x8 va[8];
#pragma unroll
        for (int f = 0; f < 8; ++f) va[f] = ld8(vt + f * 512);
        vt += 4096;

        // unconditional prefetch of next K panel (one-past read is harmless:
        // lands in the adjacent allocated vp buffer on the final panel)
#pragma unroll
        for (int f = 0; f < 8; ++f) ka[f] = ld8(kt + f * 512);
        kt += 4096;

        // softmax: p = exp2(z); C-layout -> Ps via imm-offset stores
#pragma unroll
        for (int mt = 0; mt < 2; ++mt)
#pragma unroll
            for (int nt = 0; nt < 4; ++nt) {
                f32x4 pv;
#pragma unroll
                for (int r = 0; r < 4; ++r)
                    pv[r] = __builtin_amdgcn_exp2f(s[mt][nt][r]);
                lp[mt] += pv;
#pragma unroll
                for (int r = 0; r < 4; ++r)
                    ps_w[(mt * 16 + r) * 72 + nt * 16] = __float2bfloat16(pv[r]);
            }
        __asm__ volatile("s_waitcnt lgkmcnt(0)" ::: "memory");

        // PV: A-layout P reads (imm offsets); va[f] = frag(kk=f>>2, dt=f&3)
#pragma unroll
        for (int mt = 0; mt < 2; ++mt)
#pragma unroll
            for (int kk = 0; kk < 2; ++kk) {
                bf16x8 pf = ld8(ps_r + mt * 1152 + kk * 32);
#pragma unroll
                for (int dt = 0; dt < 4; ++dt)
                    o[mt][dt] = MFMA(pf, va[kk * 4 + dt], o[mt][dt]);
            }
    }

    // per-wave row-sum over the 16-lane col group
    float lval[2][4];
#pragma unroll
    for (int mt = 0; mt < 2; ++mt)
#pragma unroll
        for (int r = 0; r < 4; ++r) {
            float v = lp[mt][r];
#pragma unroll
            for (int off = 1; off < 16; off <<= 1)
                v += __shfl_xor(v, off, 64);
            lval[mt][r] = v;
        }

    // combine the two KV-half partials through LDS
    float* cbo = (float*)smraw;        // [32][64]
    float* cbl = cbo + 2048;           // [32]
    __syncthreads();                   // both waves done with Ps
    if (wv == 1) {
#pragma unroll
        for (int mt = 0; mt < 2; ++mt)
#pragma unroll
            for (int dt = 0; dt < 4; ++dt)
#pragma unroll
                for (int r = 0; r < 4; ++r)
                    cbo[(mt * 16 + quad * 4 + r) * 64 + dt * 16 + col] = o[mt][dt][r];
        if (col == 0)
#pragma unroll
            for (int mt = 0; mt < 2; ++mt)
#pragma unroll
                for (int r = 0; r < 4; ++r)
                    cbl[mt * 16 + quad * 4 + r] = lval[mt][r];
    }
    __syncthreads();
    if (wv == 0) {
#pragma unroll
        for (int mt = 0; mt < 2; ++mt) {
#pragma unroll
            for (int r = 0; r < 4; ++r) {
                int row = mt * 16 + quad * 4 + r;
                float inv = 1.0f / (lval[mt][r] + cbl[row]);
                int grow = q0 + row;
#pragma unroll
                for (int dt = 0; dt < 4; ++dt) {
                    int d = dt * 16 + col;
                    float val = (o[mt][dt][r] + cbo[row * 64 + d]) * inv;
                    size_t idx = ((size_t)(b * 2048 + grow)) * 320 + h * 64 + d;
                    split_bf16(val, A2h[idx], A2l[idx]);
                }
            }
        }
    }
}

// ---------------------------------------------------------------------------
// Kernel 3: output projection, split-precision (error-critical GEMM).
// out[m][n] = sum_k a2[m][k]*w[n][k] + bias[n], M=16384, N=320, K=320.
// ---------------------------------------------------------------------------
__global__ __launch_bounds__(256)
void proj_kernel(const __hip_bfloat16* __restrict__ ah, const __hip_bfloat16* __restrict__ al,
                 const __hip_bfloat16* __restrict__ wh, const __hip_bfloat16* __restrict__ wl,
                 const float* __restrict__ bias,
                 float* __restrict__ out)
{
    __shared__ __align__(16) __hip_bfloat16 Ash[128 * 40];
    __shared__ __align__(16) __hip_bfloat16 Asl[128 * 40];
    __shared__ __align__(16) __hip_bfloat16 Bsh[64 * 40];
    __shared__ __align__(16) __hip_bfloat16 Bsl[64 * 40];

    const int tid  = threadIdx.x;
    const int wv   = tid >> 6;
    const int lane = tid & 63;
    const int quad = lane >> 4;
    const int col  = lane & 15;
    const int m0   = blockIdx.x * 128;
    const int n0   = blockIdx.y * 64;

    f32x4 acc[2][4];
#pragma unroll
    for (int i = 0; i < 2; ++i)
#pragma unroll
        for (int j = 0; j < 4; ++j) acc[i][j] = (f32x4){0.f, 0.f, 0.f, 0.f};

    for (int k0 = 0; k0 < 320; k0 += 32) {
        __syncthreads();
#pragma unroll
        for (int i = 0; i < 2; ++i) {
            int ch = tid + i * 256;
            int r = ch >> 2, sg = ch & 3;
            *reinterpret_cast<float4*>(&Ash[r * 40 + sg * 8]) =
                *reinterpret_cast<const float4*>(&ah[(m0 + r) * 320 + k0 + sg * 8]);
            *reinterpret_cast<float4*>(&Asl[r * 40 + sg * 8]) =
                *reinterpret_cast<const float4*>(&al[(m0 + r) * 320 + k0 + sg * 8]);
        }
        {
            int r = tid >> 2, sg = tid & 3;
            *reinterpret_cast<float4*>(&Bsh[r * 40 + sg * 8]) =
                *reinterpret_cast<const float4*>(&wh[(n0 + r) * 320 + k0 + sg * 8]);
            *reinterpret_cast<float4*>(&Bsl[r * 40 + sg * 8]) =
                *reinterpret_cast<const float4*>(&wl[(n0 + r) * 320 + k0 + sg * 8]);
        }
        __syncthreads();

        bf16x8 a0h = ld8(&Ash[(wv * 32 + col) * 40 + quad * 8]);
        bf16x8 a1h = ld8(&Ash[(wv * 32 + 16 + col) * 40 + quad * 8]);
        bf16x8 a0l = ld8(&Asl[(wv * 32 + col) * 40 + quad * 8]);
        bf16x8 a1l = ld8(&Asl[(wv * 32 + 16 + col) * 40 + quad * 8]);
#pragma unroll
        for (int nt = 0; nt < 4; ++nt) {
            bf16x8 bh = ld8(&Bsh[(nt * 16 + col) * 40 + quad * 8]);
            bf16x8 bl = ld8(&Bsl[(nt * 16 + col) * 40 + quad * 8]);
            acc[0][nt] = MFMA(a0h, bh, acc[0][nt]);
            acc[0][nt] = MFMA(a0h, bl, acc[0][nt]);
            acc[0][nt] = MFMA(a0l, bh, acc[0][nt]);
            acc[1][nt] = MFMA(a1h, bh, acc[1][nt]);
            acc[1][nt] = MFMA(a1h, bl, acc[1][nt]);
            acc[1][nt] = MFMA(a1l, bh, acc[1][nt]);
        }
    }

#pragma unroll
    for (int nt = 0; nt < 4; ++nt) {
        float bv = bias[n0 + nt * 16 + col];
#pragma unroll
        for (int mt = 0; mt < 2; ++mt) {
#pragma unroll
            for (int r = 0; r < 4; ++r) {
                int m = m0 + wv * 32 + mt * 16 + quad * 4 + r;
                out[(size_t)m * 320 + n0 + nt * 16 + col] = acc[mt][nt][r] + bv;
            }
        }
    }
}

// ---------------------------------------------------------------------------
extern "C" void kernel_launch(void* const* d_in, const int* in_sizes, int n_in,
                              void* d_out, int out_size, void* d_ws, size_t ws_size,
                              hipStream_t stream)
{
    const float* x      = (const float*)d_in[0];  // [8,2048,320]
    const float* w_qkv  = (const float*)d_in[1];  // [960,320]
    const float* w_proj = (const float*)d_in[2];  // [320,320]
    const float* b_proj = (const float*)d_in[3];  // [320]
    float* out = (float*)d_out;                   // [8,2048,320] f32

    const size_t NX = 5242880, NWQ = 307200, NWP = 102400;
    __hip_bfloat16* xb  = (__hip_bfloat16*)d_ws;  // reused as a2h after qkv
    __hip_bfloat16* wqb = xb + NX;
    __hip_bfloat16* wph = wqb + NWQ;
    __hip_bfloat16* wpl = wph + NWP;
    __hip_bfloat16* q   = wpl + NWP;              // [bh][n][d], pre-scaled
    __hip_bfloat16* kp  = q + NX;                 // K' fragment order
    __hip_bfloat16* vp  = kp + NX;                // V' fragment order (after kp:
                                                  //  one-past K prefetch lands here)
    __hip_bfloat16* a2l = vp + NX;                // [B,N,C] lo half
    __hip_bfloat16* a2h = xb;                     // alias: x dead after qkv

    split_inputs<<<1024, 256, 0, stream>>>(x, w_qkv, w_proj, xb, wqb, wph, wpl);
    qkv_kernel<<<dim3(128, 15), 256, 0, stream>>>(xb, wqb, q, kp, vp);
    attn_kernel<<<dim3(64, 40), 128, 0, stream>>>(q, kp, vp, a2h, a2l);
    proj_kernel<<<dim3(128, 5), 256, 0, stream>>>(a2h, a2l, wph, wpl, b_proj, out);
}